// Round 15
// baseline (86.463 us; speedup 1.0000x reference)
//
#include <hip/hip_runtime.h>

#define N_NODES 8192
#define N_EDGES 8192
#define DEG 32
#define D 32
#define CAP 128   // fixed CSR slots per node (Poisson(32); P(deg>128) ~ 0)
#define ROWS_PER_BLK 4

typedef float vf4 __attribute__((ext_vector_type(4)));

// Algebra (full collapse):
//   M = Wm1@Wm2@Wm3 (64x1), split M0 (node half) / M1 (edge half);
//   c = bm1@(Wm2@Wm3) + bm2@Wm3 + bm3
//   w2u = Wl2@M0 ;  v_y = Wl1@w2u ;  v_z = Wl1@M1
//   A1[e]  = sum_{unique n in e} x0[n]
//   B1[n]  = sum_{e in CSR[n]} A1[e] ;  y[n] = B1·v_y ; z[n] = B1·v_z
//   qw[e]  = sum_{n' in e} y[n'] ;  q[e] = sum_{n' in e} z[n']
//   p[n]   = c + sum_{e in CSR[n]} qw[e]
//   out[n,e] = p[n] + q[e] at incidence nonzeros, else 0.

// ---------------------------------------------------------------------------
// K1: block 0 folds weights into consts; all blocks: edge-agg1
// (dedup mask + CSR fill + A1). 8 edges/block, 32 lanes/edge.
// ---------------------------------------------------------------------------
__global__ void __launch_bounds__(256)
k1_edge(const float* __restrict__ x0, const float* __restrict__ Wl1,
        const float* __restrict__ Wl2, const float* __restrict__ Wm1,
        const float* __restrict__ bm1, const float* __restrict__ Wm2,
        const float* __restrict__ bm2, const float* __restrict__ Wm3,
        const float* __restrict__ bm3, const int* __restrict__ node_idx,
        float* __restrict__ A, unsigned* __restrict__ validmask,
        int* __restrict__ cursor, int* __restrict__ csr_e,
        float* __restrict__ consts) {
    __shared__ int sidx[8][32];
    __shared__ unsigned smask[8];
    __shared__ float fsh[128];
    const int t = threadIdx.x, el = t >> 5, s = t & 31;

    if (blockIdx.x == 0) {
        float* w23 = fsh;        // 32
        float* M0  = fsh + 32;   // 32
        float* M1  = fsh + 64;   // 32
        float* w2u = fsh + 96;   // 32
        if (t < 32) {
            float acc = 0.f;
            for (int k = 0; k < 32; ++k) acc += Wm2[t * 32 + k] * Wm3[k];
            w23[t] = acc;
        }
        __syncthreads();
        if (t < 64) {
            float acc = 0.f;
            for (int k = 0; k < 32; ++k) acc += Wm1[t * 32 + k] * w23[k];
            if (t < 32) M0[t] = acc; else M1[t - 32] = acc;
        }
        if (t == 0) {
            float c = bm3[0];
            for (int k = 0; k < 32; ++k) c += bm1[k] * w23[k] + bm2[k] * Wm3[k];
            consts[0] = c;
        }
        __syncthreads();
        if (t < 32) {
            float acc = 0.f;
            for (int d2 = 0; d2 < 32; ++d2) acc += Wl2[t * 32 + d2] * M0[d2];
            w2u[t] = acc;
        }
        __syncthreads();
        if (t < 32) {
            float ay = 0.f, az = 0.f;
            for (int d2 = 0; d2 < 32; ++d2) {
                float w = Wl1[t * 32 + d2];
                ay += w * w2u[d2];
                az += w * M1[d2];
            }
            consts[1 + t]  = ay;   // v_y
            consts[33 + t] = az;   // v_z
        }
        __syncthreads();
    }

    // ---- edge-agg1 ----
    int e = blockIdx.x * 8 + el;
    int idx = node_idx[e * DEG + s];
    sidx[el][s] = idx;
    __syncthreads();
    bool valid = true;
    for (int j = 0; j < s; ++j)
        if (sidx[el][j] == idx) { valid = false; break; }
    unsigned long long bl = __ballot(valid);
    if (s == 0) {
        unsigned m = (unsigned)(bl >> (t & 32));
        smask[el] = m;
        validmask[e] = m;
    }
    if (valid) {
        int pos = atomicAdd(&cursor[idx], 1);
        if (pos < CAP) csr_e[idx * CAP + pos] = e;
    }
    __syncthreads();
    unsigned m = smask[el];
    float acc = 0.f;
#pragma unroll
    for (int j = 0; j < 32; ++j)
        if ((m >> j) & 1u) acc += x0[sidx[el][j] * D + s];
    A[e * D + s] = acc;
}

// ---------------------------------------------------------------------------
// K2a: per node, B1 = sum of A1 rows in CSR[n]; y[n] = B1·v_y, z[n] = B1·v_z.
// 8 nodes/block, 32 lanes/node. Coalesced gathers, no atomics.
// ---------------------------------------------------------------------------
__global__ void __launch_bounds__(256)
k2_node(const float* __restrict__ A, const int* __restrict__ csr_e,
        const int* __restrict__ cursor, const float* __restrict__ consts,
        float* __restrict__ y, float* __restrict__ z) {
    const int t = threadIdx.x, el = t >> 5, s = t & 31;
    int n = blockIdx.x * 8 + el;
    int cnt = min(cursor[n], CAP);
    const int* lst = csr_e + n * CAP;
    float acc = 0.f;
    int j = 0;
    for (; j + 4 <= cnt; j += 4) {
        int4 e4 = *(const int4*)(lst + j);
        acc += A[e4.x * D + s] + A[e4.y * D + s] +
               A[e4.z * D + s] + A[e4.w * D + s];
    }
    for (; j < cnt; ++j) acc += A[lst[j] * D + s];
    float ay = acc * consts[1 + s];
    float az = acc * consts[33 + s];
#pragma unroll
    for (int off = 16; off; off >>= 1) {
        ay += __shfl_xor(ay, off);
        az += __shfl_xor(az, off);
    }
    if (s == 0) { y[n] = ay; z[n] = az; }
}

// ---------------------------------------------------------------------------
// K2b: per edge, qw[e] = sum of y over valid member nodes; q[e] = same for z.
// 8 edges/block, 32 lanes/edge; y/z tables are 32 KB (L1/L2-hot).
// ---------------------------------------------------------------------------
__global__ void __launch_bounds__(256)
k2_edge(const int* __restrict__ node_idx, const unsigned* __restrict__ validmask,
        const float* __restrict__ y, const float* __restrict__ z,
        float* __restrict__ qw, float* __restrict__ q) {
    const int t = threadIdx.x, el = t >> 5, s = t & 31;
    int e = blockIdx.x * 8 + el;
    unsigned m = validmask[e];
    int idx = node_idx[e * DEG + s];
    bool valid = (m >> s) & 1u;
    float ay = valid ? y[idx] : 0.f;
    float az = valid ? z[idx] : 0.f;
#pragma unroll
    for (int off = 16; off; off >>= 1) {
        ay += __shfl_xor(ay, off);
        az += __shfl_xor(az, off);
    }
    if (s == 0) { qw[e] = ay; q[e] = az; }
}

// ---------------------------------------------------------------------------
// K_fillpatch: block b owns ROWS_PER_BLK contiguous rows. Phase 1: stream
// 128 KB of float4 zeros over the rows (barrier-free store loop). Phase 2:
// __syncthreads (drains vmcnt -> the block's stores are globally ordered
// before its subsequent ops), then warps 0..3 patch their own row's <=CAP
// cells while the lines are still L2-resident: p = c + sum qw[eid],
// out[n,e] = p + q[e]. One dispatch replaces fill + separate cold patch.
// ---------------------------------------------------------------------------
__global__ void __launch_bounds__(256)
k_fillpatch(const int* __restrict__ csr_e, const int* __restrict__ cursor,
            const float* __restrict__ qw, const float* __restrict__ q,
            const float* __restrict__ consts, float* __restrict__ out) {
    const int t = threadIdx.x, w = t >> 5, s = t & 31;
    const int n0 = blockIdx.x * ROWS_PER_BLK;

    // Phase 1: contiguous zero-fill of rows [n0, n0+4): 8192 vf4 per block.
    vf4* dst = (vf4*)(out + (size_t)n0 * N_EDGES);
    vf4 zz = (vf4)(0.f);
#pragma unroll
    for (int k = 0; k < 32; ++k)
        dst[t + 256 * k] = zz;
    __syncthreads();   // vmcnt(0) drain: fill stores ordered before patch

    // Phase 2: warps 0..3 patch one row each (L2-hot lines).
    if (w < ROWS_PER_BLK) {
        int n = n0 + w;
        int cnt = min(cursor[n], CAP);
        const int* lst = csr_e + n * CAP;
        float acc = 0.f;
        for (int j = s; j < cnt; j += 32) acc += qw[lst[j]];
#pragma unroll
        for (int off = 16; off; off >>= 1) acc += __shfl_xor(acc, off);
        float pn = acc + consts[0];
        float* rowp = out + (size_t)n * N_EDGES;
        for (int j = s; j < cnt; j += 32) {
            int e = lst[j];
            rowp[e] = pn + q[e];
        }
    }
}

extern "C" void kernel_launch(void* const* d_in, const int* in_sizes, int n_in,
                              void* d_out, int out_size, void* d_ws, size_t ws_size,
                              hipStream_t stream) {
    const float* x0  = (const float*)d_in[0];
    // d_in[1] = dense incidence matrix: unused (sparse path).
    const float* Wl1 = (const float*)d_in[2];
    const float* Wl2 = (const float*)d_in[3];
    const float* Wm1 = (const float*)d_in[4];
    const float* bm1 = (const float*)d_in[5];
    const float* Wm2 = (const float*)d_in[6];
    const float* bm2 = (const float*)d_in[7];
    const float* Wm3 = (const float*)d_in[8];
    const float* bm3 = (const float*)d_in[9];
    const int* node_idx = (const int*)d_in[10];
    float* out = (float*)d_out;

    // Workspace layout
    char* ws = (char*)d_ws;
    int*      cursor    = (int*)(ws);                          // 32 KB
    float*    y         = (float*)(ws + ( 32u << 10));         // 32 KB
    float*    z         = (float*)(ws + ( 64u << 10));         // 32 KB
    unsigned* validmask = (unsigned*)(ws + ( 96u << 10));      // 32 KB
    float*    qw        = (float*)(ws + (128u << 10));         // 32 KB
    float*    q         = (float*)(ws + (160u << 10));         // 32 KB
    float*    consts    = (float*)(ws + (192u << 10));         // 65 floats
    float*    A         = (float*)(ws + (1u << 20));           // 1 MB [E*D]
    int*      csr_e     = (int*)(ws + (2u << 20));             // 4 MB [N*CAP]

    hipMemsetAsync(cursor, 0, N_NODES * sizeof(int), stream);
    k1_edge<<<N_EDGES / 8, 256, 0, stream>>>(x0, Wl1, Wl2, Wm1, bm1, Wm2, bm2,
                                             Wm3, bm3, node_idx, A, validmask,
                                             cursor, csr_e, consts);
    k2_node<<<N_NODES / 8, 256, 0, stream>>>(A, csr_e, cursor, consts, y, z);
    k2_edge<<<N_EDGES / 8, 256, 0, stream>>>(node_idx, validmask, y, z, qw, q);
    k_fillpatch<<<N_NODES / ROWS_PER_BLK, 256, 0, stream>>>(csr_e, cursor, qw, q,
                                                            consts, out);
}